// Round 1
// baseline (1274.304 us; speedup 1.0000x reference)
//
#include <hip/hip_runtime.h>
#include <math.h>

// WorldNet rollout: B=2048 rows, T=128 serial steps.
// 256 persistent blocks x 512 threads; each block owns 8 rows for the whole
// rollout. Weights staged in LDS (52KB, custom [j][n][kp] layout, zero-padded)
// except W3/W4 which stream from global/L2. Activations live in LDS as
// [feature][row8] so one weight read feeds up to 8 row-FMAs.

#define TSTEPS 128
#define NBATCH 2048
#define NSTATE 115
#define NACTD  39
#define NIN    154
#define NOUT   116

constexpr int NTHREADS = 512;

// ---- LDS float offsets ----
constexpr int OW0 = 0;      // 20*16*8  = 2560
constexpr int OW1 = 2560;   // 4*32*4   = 512
constexpr int OW2 = 3072;   // 4*64*8   = 2048
constexpr int OW5 = 5120;   // 4*32*16  = 2048
constexpr int OW6 = 7168;   // 4*16*8   = 512
constexpr int OW7 = 7680;   // 2*8*8    = 128
constexpr int OW8 = 7808;   // 2*128*4  = 1024
constexpr int OB0 = 8832, OB1 = 8848, OB2 = 8880, OB3 = 8944, OB4 = 9072;
constexpr int OB5 = 9136, OB6 = 9168, OB7 = 9184, OB8 = 9192;
constexpr int OWR = 9307;   // 115*3 = 345
constexpr int OBR = 9652;   // 3 (pad to 9656)
constexpr int OHA = 9656;   // 160*8 = 1280  (layer buf A, L0 input incl pad)
constexpr int OHB = 10936;  // 128*8 = 1024  (layer buf B)
constexpr int OXS = 11960;  // 115*9 = 1035  (state, stride 9 to dodge conflicts)
constexpr int LDSF = 12995; // 51,980 bytes

__device__ __forceinline__ void stage_w(const float* __restrict__ src, float* __restrict__ dst,
                                        int K, int N, int NP, int KS, int J, int tid) {
  const int sz = J * NP * KS;
  for (int p = tid; p < sz; p += NTHREADS) {
    int kp = p % KS, n = (p / KS) % NP, j = p / (KS * NP);
    int k = kp + KS * j;
    dst[p] = (k < K && n < N) ? src[k * N + n] : 0.f;
  }
}

// One dense layer over 8 rows. Thread id -> (rg, n, kp), id = rg*NP*KS + n*KS + kp.
// kp lives in the LOW lane bits so the k-split reduction is intra-wave shfl_xor.
// WLDS: weights from LDS in padded [j][n][kp] layout (coalesced, no guards);
// else from global in natural [k][n] layout (requires K%KS==0 && N==NP).
template<int K, int N, int NP, int KS, int RS, bool CLIP, bool WLDS>
__device__ __forceinline__ void layer_fwd(const float* __restrict__ wsrc,
                                          const float* __restrict__ bias,
                                          const float* __restrict__ in8,
                                          float* __restrict__ out8, int tid) {
  constexpr int RPL = 8 / RS;              // rows per lane
  constexpr int J = (K + KS - 1) / KS;     // k iterations
  static_assert(RS * NP * KS == NTHREADS, "bad layer config");
  const int kp = tid % KS;
  const int n  = (tid / KS) % NP;
  const int rg = tid / (NP * KS);
  float acc[RPL];
#pragma unroll
  for (int r = 0; r < RPL; ++r) acc[r] = 0.f;
#pragma unroll
  for (int j = 0; j < J; ++j) {
    const int k = kp + KS * j;
    float w;
    if constexpr (WLDS) w = wsrc[(j * NP + n) * KS + kp];
    else                w = wsrc[k * N + n];
    const float* ap = in8 + k * 8 + rg * RPL;
    float av[RPL];
    if constexpr (RPL == 8) {
      *(float4*)&av[0] = *(const float4*)ap;
      *(float4*)&av[4] = *(const float4*)(ap + 4);
    } else if constexpr (RPL == 4) {
      *(float4*)&av[0] = *(const float4*)ap;
    } else if constexpr (RPL == 2) {
      *(float2*)&av[0] = *(const float2*)ap;
    } else {
      av[0] = *ap;
    }
#pragma unroll
    for (int r = 0; r < RPL; ++r) acc[r] += w * av[r];
  }
#pragma unroll
  for (int m = 1; m < KS; m <<= 1) {
#pragma unroll
    for (int r = 0; r < RPL; ++r) acc[r] += __shfl_xor(acc[r], m, 64);
  }
  if (kp == 0 && n < N) {
    const float b = bias[n];
    float ov[RPL];
#pragma unroll
    for (int r = 0; r < RPL; ++r) {
      float v = acc[r] + b;
      if constexpr (CLIP) v = fminf(fmaxf(v, 0.f), 6.f);
      ov[r] = v;
    }
    float* op = out8 + n * 8 + rg * RPL;
    if constexpr (RPL == 8) { *(float4*)op = *(float4*)&ov[0]; *(float4*)(op + 4) = *(float4*)&ov[4]; }
    else if constexpr (RPL == 4) { *(float4*)op = *(float4*)&ov[0]; }
    else if constexpr (RPL == 2) { *(float2*)op = *(float2*)&ov[0]; }
    else { *op = ov[0]; }
  }
}

__global__ __launch_bounds__(NTHREADS)
void worldnet_kernel(const float* __restrict__ u,
                     const float* __restrict__ W0, const float* __restrict__ b0,
                     const float* __restrict__ W1, const float* __restrict__ b1,
                     const float* __restrict__ W2, const float* __restrict__ b2,
                     const float* __restrict__ W3, const float* __restrict__ b3,
                     const float* __restrict__ W4, const float* __restrict__ b4,
                     const float* __restrict__ W5, const float* __restrict__ b5,
                     const float* __restrict__ W6, const float* __restrict__ b6,
                     const float* __restrict__ W7, const float* __restrict__ b7,
                     const float* __restrict__ W8, const float* __restrict__ b8,
                     const float* __restrict__ Wr, const float* __restrict__ br,
                     float* __restrict__ out) {
  __shared__ __align__(16) float lds[LDSF];
  const int tid = threadIdx.x;
  const int w = tid >> 6, lane = tid & 63;   // wave w owns row w of this block

  // ---- one-time staging ----
  stage_w(W0, &lds[OW0], 154, 16, 16, 8, 20, tid);
  stage_w(W1, &lds[OW1], 16, 32, 32, 4, 4, tid);
  stage_w(W2, &lds[OW2], 32, 64, 64, 8, 4, tid);
  stage_w(W5, &lds[OW5], 64, 32, 32, 16, 4, tid);
  stage_w(W6, &lds[OW6], 32, 16, 16, 8, 4, tid);
  stage_w(W7, &lds[OW7], 16, 8, 8, 8, 2, tid);
  stage_w(W8, &lds[OW8], 8, 115, 128, 4, 2, tid);
  if (tid < 16)  lds[OB0 + tid] = b0[tid];
  if (tid < 32)  lds[OB1 + tid] = b1[tid];
  if (tid < 64)  lds[OB2 + tid] = b2[tid];
  if (tid < 128) lds[OB3 + tid] = b3[tid];
  if (tid < 64)  lds[OB4 + tid] = b4[tid];
  if (tid < 32)  lds[OB5 + tid] = b5[tid];
  if (tid < 16)  lds[OB6 + tid] = b6[tid];
  if (tid < 8)   lds[OB7 + tid] = b7[tid];
  if (tid < 115) lds[OB8 + tid] = b8[tid];
  if (tid < 345) lds[OWR + tid] = Wr[tid];
  if (tid < 3)   lds[OBR + tid] = br[tid];
  // zero the L0 k-padding tail of hA (k in [154,160))
  for (int p = 154 * 8 + tid; p < 160 * 8; p += NTHREADS) lds[OHA + p] = 0.f;

  const long brow = (long)blockIdx.x * 8 + w;
  const float* urow = u + (size_t)brow * TSTEPS * NIN;
  float* orow = out + (size_t)brow * TSTEPS * NOUT;

  // x0 = u[:,0,:115]
  lds[OXS + lane * 9 + w] = urow[lane];
  if (lane < NSTATE - 64) lds[OXS + (lane + 64) * 9 + w] = urow[lane + 64];
  __syncthreads();

  float* hA = &lds[OHA];
  float* hB = &lds[OHB];
  float* xs = &lds[OXS];

  for (int t = 0; t < TSTEPS; ++t) {
    const float* ut = urow + (size_t)t * NIN;
    float* ot = orow + (size_t)t * NOUT;

    // write x_t to out (wave-parallel, coalesced per row)
    ot[lane] = xs[lane * 9 + w];
    if (lane < NSTATE - 64) ot[lane + 64] = xs[(lane + 64) * 9 + w];
    // load a_t into hA[115..154)
    if (lane < NACTD) hA[(NSTATE + lane) * 8 + w] = ut[NSTATE + lane];
    // copy x into hA[0..115) (flat, [feat][row8] layout)
    for (int i = tid; i < NSTATE * 8; i += NTHREADS) hA[i] = xs[(i >> 3) * 9 + (i & 7)];
    __syncthreads();

    layer_fwd<154, 16, 16, 8, 4, true,  true >(&lds[OW0], &lds[OB0], hA, hB, tid); __syncthreads();
    layer_fwd<16,  32, 32, 4, 4, true,  true >(&lds[OW1], &lds[OB1], hB, hA, tid); __syncthreads();
    layer_fwd<32,  64, 64, 8, 1, true,  true >(&lds[OW2], &lds[OB2], hA, hB, tid); __syncthreads();
    layer_fwd<64, 128, 128, 4, 1, true, false>(W3,        &lds[OB3], hB, hA, tid); __syncthreads();
    layer_fwd<128, 64, 64, 8, 1, true,  false>(W4,        &lds[OB4], hA, hB, tid); __syncthreads();
    layer_fwd<64,  32, 32, 16, 1, true, true >(&lds[OW5], &lds[OB5], hB, hA, tid); __syncthreads();
    layer_fwd<32,  16, 16, 8, 4, true,  true >(&lds[OW6], &lds[OB6], hA, hB, tid); __syncthreads();
    layer_fwd<16,   8,  8, 8, 8, true,  true >(&lds[OW7], &lds[OB7], hB, hA, tid); __syncthreads();
    layer_fwd<8,  115, 128, 4, 1, false, true>(&lds[OW8], &lds[OB8], hA, hB, tid); __syncthreads();

    // x_{t+1} = x_t + mlp_out
    for (int i = tid; i < NSTATE * 8; i += NTHREADS) xs[(i >> 3) * 9 + (i & 7)] += hB[i];
    __syncthreads();

    // reward_t = -|| x_{t+1} @ Wr + br ||  (wave-parallel per row)
    {
      const float* WrL = &lds[OWR];
      float xa = xs[lane * 9 + w];
      float p0 = xa * WrL[lane * 3 + 0];
      float p1 = xa * WrL[lane * 3 + 1];
      float p2 = xa * WrL[lane * 3 + 2];
      if (lane < NSTATE - 64) {
        float xb = xs[(lane + 64) * 9 + w];
        p0 += xb * WrL[(lane + 64) * 3 + 0];
        p1 += xb * WrL[(lane + 64) * 3 + 1];
        p2 += xb * WrL[(lane + 64) * 3 + 2];
      }
#pragma unroll
      for (int m = 1; m < 64; m <<= 1) {
        p0 += __shfl_xor(p0, m, 64);
        p1 += __shfl_xor(p1, m, 64);
        p2 += __shfl_xor(p2, m, 64);
      }
      float r0 = p0 + lds[OBR + 0];
      float r1 = p1 + lds[OBR + 1];
      float r2 = p2 + lds[OBR + 2];
      if (lane == 0) ot[NOUT - 1] = -sqrtf(r0 * r0 + r1 * r1 + r2 * r2);
    }
    // no barrier needed: next iteration only READS xs before the next barrier,
    // and hA writes (a_t / x copy) touch regions whose last reader (L8) is
    // already behind a barrier.
  }
}

extern "C" void kernel_launch(void* const* d_in, const int* in_sizes, int n_in,
                              void* d_out, int out_size, void* d_ws, size_t ws_size,
                              hipStream_t stream) {
  const float* u  = (const float*)d_in[0];
  const float* W0 = (const float*)d_in[1];  const float* b0 = (const float*)d_in[2];
  const float* W1 = (const float*)d_in[3];  const float* b1 = (const float*)d_in[4];
  const float* W2 = (const float*)d_in[5];  const float* b2 = (const float*)d_in[6];
  const float* W3 = (const float*)d_in[7];  const float* b3 = (const float*)d_in[8];
  const float* W4 = (const float*)d_in[9];  const float* b4 = (const float*)d_in[10];
  const float* W5 = (const float*)d_in[11]; const float* b5 = (const float*)d_in[12];
  const float* W6 = (const float*)d_in[13]; const float* b6 = (const float*)d_in[14];
  const float* W7 = (const float*)d_in[15]; const float* b7 = (const float*)d_in[16];
  const float* W8 = (const float*)d_in[17]; const float* b8 = (const float*)d_in[18];
  const float* Wr = (const float*)d_in[19]; const float* br = (const float*)d_in[20];
  float* out = (float*)d_out;
  (void)in_sizes; (void)n_in; (void)out_size; (void)d_ws; (void)ws_size;

  dim3 grid(NBATCH / 8), block(NTHREADS);
  hipLaunchKernelGGL(worldnet_kernel, grid, block, 0, stream,
                     u, W0, b0, W1, b1, W2, b2, W3, b3, W4, b4,
                     W5, b5, W6, b6, W7, b7, W8, b8, Wr, br, out);
}

// Round 2
// 803.387 us; speedup vs baseline: 1.5862x; 1.5862x over previous
//
#include <hip/hip_runtime.h>
#include <math.h>

// WorldNet rollout: B=2048 rows, T=128 serial steps, 9-layer MLP + reward.
// R2: weights live in per-thread VGPRs (static (kp,n)->thread map, ~107 f32),
// k-split reductions on the VALU pipe via DPP (xor1,xor2,half_mirror,mirror),
// acts in LDS [feat][4rows] float4. 512 blocks x 256 threads, 4 rows/block,
// 2 blocks/CU so barriers overlap. DS pipe only carries act reads/writes.

#define TSTEPS 128
#define NB     2048
#define NST    115
#define NACT   39
#define NINF   154
#define NOUTF  116
constexpr int NT   = 256;
constexpr int ROWS = 4;

// ---- DPP reduction (VALU pipe, no DS ops) ----
template<int CTRL>
__device__ __forceinline__ float dpp_add(float x) {
  int y = __builtin_amdgcn_update_dpp(0, __float_as_int(x), CTRL, 0xF, 0xF, true);
  return x + __int_as_float(y);
}
// Sum over the KS-lane group in the low lane bits (KS in {2,4,8,16}).
// xor1=quad_perm[1,0,3,2]=0xB1, xor2=quad_perm[2,3,0,1]=0x4E,
// xor7=ROW_HALF_MIRROR=0x141, xor15=ROW_MIRROR=0x140.
template<int KS>
__device__ __forceinline__ float kreduce(float a) {
  if constexpr (KS >= 2)  a = dpp_add<0xB1>(a);
  if constexpr (KS >= 4)  a = dpp_add<0x4E>(a);
  if constexpr (KS >= 8)  a = dpp_add<0x141>(a);
  if constexpr (KS >= 16) a = dpp_add<0x140>(a);
  return a;
}

// Thread map: tid = kp + KS*(cg + NP*rg).  Thread holds weights W[k][n] for
// k = kp + KS*j (j<J) and n = cg + c*NP (c<NC); computes RPL = ROWS/RS rows.
template<int K, int NW, int NP, int NC, int KS, int RS, int J>
__device__ __forceinline__ void wload(const float* __restrict__ Wg,
                                      const float* __restrict__ bg,
                                      float (&w)[J][NC], float (&b)[NC], int tid) {
  static_assert(NP * KS * RS == NT, "bad cfg");
  const int kp = tid % KS, rest = tid / KS, cg = rest % NP;
#pragma unroll
  for (int j = 0; j < J; ++j)
#pragma unroll
    for (int c = 0; c < NC; ++c) {
      const int k = kp + KS * j, n = cg + c * NP;
      w[j][c] = (k < K && n < NW) ? Wg[k * NW + n] : 0.f;   // zero-pad: garbage acts are harmless
    }
#pragma unroll
  for (int c = 0; c < NC; ++c) {
    const int n = cg + c * NP;
    b[c] = (n < NW) ? bg[n] : 0.f;
  }
}

template<int K, int NW, int NP, int NC, int KS, int RS, int J, bool CLIP>
__device__ __forceinline__ void lrun(const float (&w)[J][NC], const float (&b)[NC],
                                     const float* __restrict__ in,
                                     float* __restrict__ out, int tid) {
  constexpr int RPL = ROWS / RS;
  const int kp = tid % KS, rest = tid / KS, cg = rest % NP, rg = rest / NP;
  float acc[NC][RPL];
#pragma unroll
  for (int c = 0; c < NC; ++c)
#pragma unroll
    for (int r = 0; r < RPL; ++r) acc[c][r] = 0.f;

#pragma unroll
  for (int j = 0; j < J; ++j) {
    const int k = kp + KS * j;
    const float* ap = in + k * ROWS + rg * RPL;
    float av[RPL];
    if constexpr (RPL == 4) {
      float4 t = *(const float4*)ap; av[0]=t.x; av[1]=t.y; av[2]=t.z; av[3]=t.w;
    } else if constexpr (RPL == 2) {
      float2 t = *(const float2*)ap; av[0]=t.x; av[1]=t.y;
    } else {
      av[0] = *ap;
    }
#pragma unroll
    for (int c = 0; c < NC; ++c)
#pragma unroll
      for (int r = 0; r < RPL; ++r) acc[c][r] += w[j][c] * av[r];
  }
#pragma unroll
  for (int c = 0; c < NC; ++c)
#pragma unroll
    for (int r = 0; r < RPL; ++r) acc[c][r] = kreduce<KS>(acc[c][r]);

  if (kp == 0) {
#pragma unroll
    for (int c = 0; c < NC; ++c) {
      const int n = cg + c * NP;
      bool ok = true;
      if constexpr (NP * NC > NW) ok = (n < NW);
      if (ok) {
        float ov[RPL];
#pragma unroll
        for (int r = 0; r < RPL; ++r) {
          float v = acc[c][r] + b[c];
          if constexpr (CLIP) v = fminf(fmaxf(v, 0.f), 6.f);
          ov[r] = v;
        }
        float* op = out + n * ROWS + rg * RPL;
        if constexpr (RPL == 4)      *(float4*)op = make_float4(ov[0], ov[1], ov[2], ov[3]);
        else if constexpr (RPL == 2) *(float2*)op = make_float2(ov[0], ov[1]);
        else                         *op = ov[0];
      }
    }
  }
}

__global__ __launch_bounds__(NT, 2)
void worldnet_kernel(const float* __restrict__ u,
                     const float* __restrict__ W0, const float* __restrict__ b0,
                     const float* __restrict__ W1, const float* __restrict__ b1,
                     const float* __restrict__ W2, const float* __restrict__ b2,
                     const float* __restrict__ W3, const float* __restrict__ b3,
                     const float* __restrict__ W4, const float* __restrict__ b4,
                     const float* __restrict__ W5, const float* __restrict__ b5,
                     const float* __restrict__ W6, const float* __restrict__ b6,
                     const float* __restrict__ W7, const float* __restrict__ b7,
                     const float* __restrict__ W8, const float* __restrict__ b8,
                     const float* __restrict__ Wr, const float* __restrict__ br,
                     float* __restrict__ out) {
  __shared__ __align__(16) float sIN[160 * ROWS];  // x(115) | acts(39) | zero pad(6)
  __shared__ __align__(16) float sA[128 * ROWS];
  __shared__ __align__(16) float sB[128 * ROWS];
  const int tid = threadIdx.x, wv = tid >> 6, lane = tid & 63;

  // ---- per-thread register weights ----
  float w0[10][1], w1[2][1], w2[4][2], w3[8][4], w4[8][4],
        w5[4][2],  w6[2][1], w7[1][1], w8[4][1], wR[8][1];
  float c0[1], c1[1], c2[2], c3[4], c4[4], c5[2], c6[1], c7[1], c8[1], cR[1];
  wload<154, 16,  16, 1, 16, 1, 10>(W0, b0, w0, c0, tid);
  wload< 16, 32,  32, 1,  8, 1,  2>(W1, b1, w1, c1, tid);
  wload< 32, 64,  32, 2,  8, 1,  4>(W2, b2, w2, c2, tid);
  wload< 64, 128, 32, 4,  8, 1,  8>(W3, b3, w3, c3, tid);
  wload<128, 64,  16, 4, 16, 1,  8>(W4, b4, w4, c4, tid);
  wload< 64, 32,  16, 2, 16, 1,  4>(W5, b5, w5, c5, tid);
  wload< 32, 16,  16, 1, 16, 1,  2>(W6, b6, w6, c6, tid);
  wload< 16,  8,   8, 1, 16, 2,  1>(W7, b7, w7, c7, tid);
  wload<  8, 115, 128, 1, 2, 1,  4>(W8, b8, w8, c8, tid);
  wload<115,  3,   4, 1, 16, 4,  8>(Wr, br, wR, cR, tid);

  const size_t row = (size_t)blockIdx.x * ROWS + wv;   // wave wv owns row wv
  const float* urow = u + row * (size_t)(TSTEPS * NINF);
  float* orow = out + row * (size_t)(TSTEPS * NOUTF);

  // x0 = u[:,0,:115]; zero the L0 pad feats [154,160)
  sIN[lane * ROWS + wv] = urow[lane];
  if (lane < NST - 64) sIN[(lane + 64) * ROWS + wv] = urow[lane + 64];
  if (tid < (160 - NINF) * ROWS) sIN[NINF * ROWS + tid] = 0.f;
  __syncthreads();

#pragma unroll 1
  for (int t = 0; t < TSTEPS; ++t) {
    const float* ut = urow + (size_t)t * NINF;
    float* ot = orow + (size_t)t * NOUTF;

    // write x_t, stage a_t (wave-parallel per row)
    ot[lane] = sIN[lane * ROWS + wv];
    if (lane < NST - 64) ot[lane + 64] = sIN[(lane + 64) * ROWS + wv];
    if (lane < NACT) sIN[(NST + lane) * ROWS + wv] = ut[NST + lane];
    __syncthreads();

    lrun<154, 16,  16, 1, 16, 1, 10, true >(w0, c0, sIN, sA, tid); __syncthreads();
    lrun< 16, 32,  32, 1,  8, 1,  2, true >(w1, c1, sA, sB, tid); __syncthreads();
    lrun< 32, 64,  32, 2,  8, 1,  4, true >(w2, c2, sB, sA, tid); __syncthreads();
    lrun< 64, 128, 32, 4,  8, 1,  8, true >(w3, c3, sA, sB, tid); __syncthreads();
    lrun<128, 64,  16, 4, 16, 1,  8, true >(w4, c4, sB, sA, tid); __syncthreads();
    lrun< 64, 32,  16, 2, 16, 1,  4, true >(w5, c5, sA, sB, tid); __syncthreads();
    lrun< 32, 16,  16, 1, 16, 1,  2, true >(w6, c6, sB, sA, tid); __syncthreads();
    lrun< 16,  8,   8, 1, 16, 2,  1, true >(w7, c7, sA, sB, tid); __syncthreads();
    lrun<  8, 115, 128, 1, 2, 1,  4, false>(w8, c8, sB, sA, tid); __syncthreads();

    // x_{t+1} = x_t + delta
    for (int i = tid; i < NST * ROWS; i += NT) sIN[i] += sA[i];
    __syncthreads();

    // reward_t = -||x_{t+1} @ Wr + br||; map: kp=tid%16, cg=(tid/16)%4 (=col),
    // rg=tid/64 (=row=wv). Wr rows k>=115 are zero regs, so reading the acts
    // region of sIN (k in [115,128)) is harmless.
    {
      const int kp = tid & 15;
      float p = 0.f;
#pragma unroll
      for (int j = 0; j < 8; ++j) {
        const int k = kp + 16 * j;
        p += wR[j][0] * sIN[k * ROWS + wv];
      }
      p = kreduce<16>(p);
      p += cR[0];
      float s0 = __shfl(p, 0, 64);
      float s1 = __shfl(p, 16, 64);
      float s2 = __shfl(p, 32, 64);
      if (lane == 0) ot[NST] = -sqrtf(s0 * s0 + s1 * s1 + s2 * s2);
    }
    // next iteration's sIN writes are either behind barriers or touch only the
    // zero-weight region for concurrent readers.
  }
}

extern "C" void kernel_launch(void* const* d_in, const int* in_sizes, int n_in,
                              void* d_out, int out_size, void* d_ws, size_t ws_size,
                              hipStream_t stream) {
  const float* u  = (const float*)d_in[0];
  const float* W0 = (const float*)d_in[1];  const float* b0 = (const float*)d_in[2];
  const float* W1 = (const float*)d_in[3];  const float* b1 = (const float*)d_in[4];
  const float* W2 = (const float*)d_in[5];  const float* b2 = (const float*)d_in[6];
  const float* W3 = (const float*)d_in[7];  const float* b3 = (const float*)d_in[8];
  const float* W4 = (const float*)d_in[9];  const float* b4 = (const float*)d_in[10];
  const float* W5 = (const float*)d_in[11]; const float* b5 = (const float*)d_in[12];
  const float* W6 = (const float*)d_in[13]; const float* b6 = (const float*)d_in[14];
  const float* W7 = (const float*)d_in[15]; const float* b7 = (const float*)d_in[16];
  const float* W8 = (const float*)d_in[17]; const float* b8 = (const float*)d_in[18];
  const float* Wr = (const float*)d_in[19]; const float* br = (const float*)d_in[20];
  float* out = (float*)d_out;
  (void)in_sizes; (void)n_in; (void)out_size; (void)d_ws; (void)ws_size;

  dim3 grid(NB / ROWS), block(NT);
  hipLaunchKernelGGL(worldnet_kernel, grid, block, 0, stream,
                     u, W0, b0, W1, b1, W2, b2, W3, b3, W4, b4,
                     W5, b5, W6, b6, W7, b7, W8, b8, Wr, br, out);
}